// Round 11
// baseline (160.915 us; speedup 1.0000x reference)
//
#include <hip/hip_runtime.h>
#include <hip/hip_bf16.h>

typedef __attribute__((ext_vector_type(8))) short short8;
typedef __attribute__((ext_vector_type(4))) float f32x4;
typedef __attribute__((ext_vector_type(2))) short s16x2;

#define NFEAT 128
#define DEG 32
#define FSCALE 24.0f            // feats int8 scale
#define FDEC (1.0f / (24.0f * 32.0f))
#define YSCALE 64.0f            // Y2 int8 scale
#define YDEC (1.0f / (64.0f * 32.0f))

static __device__ __forceinline__ unsigned short f2bf(float f) {
    unsigned u = __float_as_uint(f);
    u += 0x7fffu + ((u >> 16) & 1u);   // round-to-nearest-even
    return (unsigned short)(u >> 16);
}
static __device__ __forceinline__ int sxt8(unsigned x) {
    return (int)(signed char)(x & 0xffu);
}
static __device__ __forceinline__ s16x2 shfl_pk(s16x2 v, int m) {
    int x = __builtin_bit_cast(int, v);
    x = __shfl_xor(x, m);
    return __builtin_bit_cast(s16x2, x);
}

// --- combined prep: feats cvt (bf16+int8) | pack W1 | pack W2 ---
__global__ void prep_all_kernel(const float* __restrict__ feats,
                                unsigned short* __restrict__ featsb,
                                unsigned* __restrict__ feats8,
                                const float* __restrict__ W1,
                                unsigned short* __restrict__ W1p,
                                const float* __restrict__ W2,
                                unsigned short* __restrict__ W2p,
                                int n4, int nPrepBlocks, int L) {
    int b = blockIdx.x;
    if (b < nPrepBlocks) {
        int i = b * 256 + threadIdx.x;
        if (i < n4) {
            float4 f = ((const float4*)feats)[i];
            ushort4 ob;
            ob.x = f2bf(f.x); ob.y = f2bf(f.y); ob.z = f2bf(f.z); ob.w = f2bf(f.w);
            ((ushort4*)featsb)[i] = ob;
            int a0 = max(-127, min(127, __float2int_rn(f.x * FSCALE)));
            int a1 = max(-127, min(127, __float2int_rn(f.y * FSCALE)));
            int a2 = max(-127, min(127, __float2int_rn(f.z * FSCALE)));
            int a3 = max(-127, min(127, __float2int_rn(f.w * FSCALE)));
            feats8[i] = (unsigned)(a0 & 0xff) | ((unsigned)(a1 & 0xff) << 8) |
                        ((unsigned)(a2 & 0xff) << 16) | ((unsigned)(a3 & 0xff) << 24);
        }
    } else if (b < nPrepBlocks + 128) {
        int t = (b - nPrepBlocks) * 256 + threadIdx.x;   // < 32768
        int j    = t & 7;
        int lane = (t >> 3) & 63;
        int ks   = (t >> 9) & 7;
        int nt   = t >> 12;
        int k    = ks * 32 + (lane >> 4) * 8 + j;
        int col  = nt * 16 + (lane & 15);
        W1p[t] = f2bf(W1[k * 128 + col]);
    } else {
        int t = (b - nPrepBlocks - 128) * 256 + threadIdx.x;
        if (t < 7 * 4 * 64 * 8) {
            int j    = t & 7;
            int lane = (t >> 3) & 63;
            int ks   = (t >> 9) & 3;
            int nt   = t >> 11;
            int k    = ks * 32 + (lane >> 4) * 8 + j;
            int p    = nt * 16 + (lane & 15);
            float v = 0.f;
            if (p < 48) { if (p < L) v = W2[k * L + p]; }
            else        { int cc = p - 48; if (cc < L) v = W2[(128 + k) * L + cc]; }
            W2p[t] = f2bf(v);
        }
    }
}

// --- fused layer1+gemm2: 512 thr / 8 waves / 32 rows per block ---
// Phase1: int8 gathers (16B/lane, 8 lanes/row), packed-i16 unpack+reduce.
// Phase2: z1[32x256bf16] @ W1p -> h1.  Phase3: h1 (LDS) @ W2p -> X2/Y2.
__global__ __launch_bounds__(512, 8) void layer1_fused_kernel(
    const unsigned short* __restrict__ tableb,  // featsb [N][128] bf16
    const unsigned char* __restrict__ table8,   // feats8 [N][128] int8
    const int* __restrict__ neigh,              // [N][32]
    const unsigned short* __restrict__ W1p,
    const float* __restrict__ b1,
    const unsigned short* __restrict__ W2p,
    const float* __restrict__ b2,
    float* __restrict__ X2,                     // [N][L]
    signed char* __restrict__ Y2,               // [N][64]
    int nRows, int L)
{
    __shared__ unsigned int z1[32 * 128];     // 16 KB: 32 rows x 512B, XOR-swizzled
    __shared__ unsigned int h1s[32 * 68];     // 8.5 KB: 32 rows x 272B (bank-skewed)
    const int tid = threadIdx.x;
    const int w = tid >> 6;       // wave 0..7
    const int l = tid & 63;
    const int jg = l >> 3;        // neighbor subgroup 0..7 (owns 4 neighbors)
    const int c = l & 7;          // 16B chunk of the 128B int8 row

    // ---- self rows (bf16): 512 threads x 1 uint4 covers 32 rows ----
    int srow = tid >> 4, sch = tid & 15;
    int sr = min(blockIdx.x * 32 + srow, nRows - 1);
    uint4 selfv = ((const uint4*)(tableb + (size_t)sr * NFEAT))[sch];

    // ---- neighbor indices for the wave's 4 rows ----
    const int r0 = blockIdx.x * 32 + w * 4;
    const int* nbp0 = neigh + (size_t)min(r0 + 0, nRows - 1) * DEG;
    const int* nbp1 = neigh + (size_t)min(r0 + 1, nRows - 1) * DEG;
    const int* nbp2 = neigh + (size_t)min(r0 + 2, nRows - 1) * DEG;
    const int* nbp3 = neigh + (size_t)min(r0 + 3, nRows - 1) * DEG;
    int i00 = nbp0[jg], i01 = nbp0[8 + jg], i02 = nbp0[16 + jg], i03 = nbp0[24 + jg];
    int i10 = nbp1[jg], i11 = nbp1[8 + jg], i12 = nbp1[16 + jg], i13 = nbp1[24 + jg];
    int i20 = nbp2[jg], i21 = nbp2[8 + jg], i22 = nbp2[16 + jg], i23 = nbp2[24 + jg];
    int i30 = nbp3[jg], i31 = nbp3[8 + jg], i32 = nbp3[16 + jg], i33 = nbp3[24 + jg];

    const char* tb8 = (const char*)table8;
    const size_t co = (size_t)(16 * c);
#define GLD16(j) (*(const uint4*)(tb8 + (size_t)(j) * 128 + co))
#define GATH4(A, a, b_, c_, d_) \
    uint4 A##0 = GLD16(a), A##1 = GLD16(b_), A##2 = GLD16(c_), A##3 = GLD16(d_);

    GATH4(vA, i00, i01, i02, i03)
    GATH4(vB, i10, i11, i12, i13)

    // self-row LDS write (waits only on selfv)
    *(uint4*)((char*)z1 + srow * 512 + ((16 * sch) ^ ((srow & 7) << 4))) = selfv;

    GATH4(vC, i20, i21, i22, i23)

    // packed-i16 consume: e[d]={f+0,f+2}, o[d]={f+1,f+3} per dword d
#define UNPK_PK(vd, d)                                                        \
    {                                                                         \
        unsigned _v = (vd);                                                   \
        e[d] += (__builtin_bit_cast(s16x2, (unsigned)(_v << 8)) >> 8);        \
        o[d] += (__builtin_bit_cast(s16x2, _v) >> 8);                         \
    }
#define CONSUME_PK(A, rowi)                                                          \
    {                                                                                \
        uint4 q0 = A##0, q1 = A##1, q2 = A##2, q3 = A##3;                            \
        s16x2 e[4] = {(s16x2)0, (s16x2)0, (s16x2)0, (s16x2)0};                       \
        s16x2 o[4] = {(s16x2)0, (s16x2)0, (s16x2)0, (s16x2)0};                       \
        UNPK_PK(q0.x, 0) UNPK_PK(q0.y, 1) UNPK_PK(q0.z, 2) UNPK_PK(q0.w, 3)          \
        UNPK_PK(q1.x, 0) UNPK_PK(q1.y, 1) UNPK_PK(q1.z, 2) UNPK_PK(q1.w, 3)          \
        UNPK_PK(q2.x, 0) UNPK_PK(q2.y, 1) UNPK_PK(q2.z, 2) UNPK_PK(q2.w, 3)          \
        UNPK_PK(q3.x, 0) UNPK_PK(q3.y, 1) UNPK_PK(q3.z, 2) UNPK_PK(q3.w, 3)          \
        _Pragma("unroll") for (int d = 0; d < 4; ++d) {                              \
            e[d] += shfl_pk(e[d], 8);  o[d] += shfl_pk(o[d], 8);                     \
            e[d] += shfl_pk(e[d], 16); o[d] += shfl_pk(o[d], 16);                    \
            e[d] += shfl_pk(e[d], 32); o[d] += shfl_pk(o[d], 32);                    \
        }                                                                            \
        if (jg == 0) {                                                               \
            int row = w * 4 + rowi;                                                  \
            int swz = (row & 7) << 4;                                                \
            uint4 m0, m1;                                                            \
            unsigned* mw0 = (unsigned*)&m0;                                          \
            unsigned* mw1 = (unsigned*)&m1;                                          \
            _Pragma("unroll") for (int d = 0; d < 2; ++d) {                          \
                mw0[2*d]   = ((unsigned)f2bf((float)o[d].x * FDEC) << 16) |          \
                             (unsigned)f2bf((float)e[d].x * FDEC);                   \
                mw0[2*d+1] = ((unsigned)f2bf((float)o[d].y * FDEC) << 16) |          \
                             (unsigned)f2bf((float)e[d].y * FDEC);                   \
                mw1[2*d]   = ((unsigned)f2bf((float)o[d+2].x * FDEC) << 16) |        \
                             (unsigned)f2bf((float)e[d+2].x * FDEC);                 \
                mw1[2*d+1] = ((unsigned)f2bf((float)o[d+2].y * FDEC) << 16) |        \
                             (unsigned)f2bf((float)e[d+2].y * FDEC);                 \
            }                                                                        \
            *(uint4*)((char*)z1 + row * 512 + ((256 + 32 * c) ^ swz)) = m0;          \
            *(uint4*)((char*)z1 + row * 512 + ((256 + 32 * c + 16) ^ swz)) = m1;     \
        }                                                                            \
    }

    CONSUME_PK(vA, 0)
    GATH4(vD, i30, i31, i32, i33)
    CONSUME_PK(vB, 1)
    CONSUME_PK(vC, 2)
    CONSUME_PK(vD, 3)
#undef GLD16
#undef GATH4
#undef UNPK_PK
#undef CONSUME_PK
    __syncthreads();

    // ---- Phase 2: [32 x 256] @ [256 x 128] -> h1 ----
    // wave w: row-tile rt = w>>2 (rows rt*16..+15), n-tiles nt0=(w&3)*2, nt0+1
    f32x4 macc0 = (f32x4){0.f,0.f,0.f,0.f}, macc1 = (f32x4){0.f,0.f,0.f,0.f};
    const int rt = w >> 2;
    const int nt0 = (w & 3) * 2;
    {
        const int arow = rt * 16 + (l & 15);
        const int aswz = (arow & 7) << 4;
        const char* zbase = (const char*)z1 + arow * 512;
#pragma unroll
        for (int ks = 0; ks < 8; ++ks) {
            int kb = (ks * 64 + ((l >> 4) * 16)) ^ aswz;
            short8 a = *(const short8*)(zbase + kb);
            short8 b0 = *(const short8*)(W1p + ((size_t)((nt0 + 0) * 8 + ks) * 64 + l) * 8);
            short8 b1f = *(const short8*)(W1p + ((size_t)((nt0 + 1) * 8 + ks) * 64 + l) * 8);
            macc0 = __builtin_amdgcn_mfma_f32_16x16x32_bf16(a, b0, macc0, 0, 0, 0);
            macc1 = __builtin_amdgcn_mfma_f32_16x16x32_bf16(a, b1f, macc1, 0, 0, 0);
        }
    }

    // ---- Phase 3a: bias+relu, h1 tile [32][128] bf16 -> h1s (272B row stride) ----
    // no barrier needed vs phase2: different LDS buffer, macc dependency orders us
#pragma unroll
    for (int tt = 0; tt < 2; ++tt) {
        int col = (nt0 + tt) * 16 + (l & 15);
        float bv = b1[col];
        f32x4 m = tt ? macc1 : macc0;
#pragma unroll
        for (int r2 = 0; r2 < 4; ++r2) {
            int row = rt * 16 + (l >> 4) * 4 + r2;
            float v = fmaxf(m[r2] + bv, 0.f);
            *(unsigned short*)((char*)h1s + row * 272 + col * 2) = f2bf(v);
        }
    }
    __syncthreads();

    // ---- Phase 3b: [32 x 128] @ [128 x 112p] -> X2/Y2 ----
    f32x4 acc2a = (f32x4){0.f,0.f,0.f,0.f}, acc2b = (f32x4){0.f,0.f,0.f,0.f};
    const int ntA = w & 3, ntB = 4 + (w & 3);
    {
        const int arow = rt * 16 + (l & 15);
        const char* hb = (const char*)h1s + arow * 272;
#pragma unroll
        for (int ks2 = 0; ks2 < 4; ++ks2) {
            short8 a = *(const short8*)(hb + ks2 * 64 + ((l >> 4) * 16));
            short8 bA = *(const short8*)(W2p + ((size_t)(ntA * 4 + ks2) * 64 + l) * 8);
            acc2a = __builtin_amdgcn_mfma_f32_16x16x32_bf16(a, bA, acc2a, 0, 0, 0);
            if (ntB < 7) {
                short8 bB = *(const short8*)(W2p + ((size_t)(ntB * 4 + ks2) * 64 + l) * 8);
                acc2b = __builtin_amdgcn_mfma_f32_16x16x32_bf16(a, bB, acc2b, 0, 0, 0);
            }
        }
    }

    // ---- epilogue: X2 f32 (+b2) cols<48, Y2 int8 cols 48..111 ----
#pragma unroll
    for (int part = 0; part < 2; ++part) {
        int nt = part ? ntB : ntA;
        if (nt >= 7) continue;
        f32x4 av = part ? acc2b : acc2a;
        int col = nt * 16 + (l & 15);
#pragma unroll
        for (int r2 = 0; r2 < 4; ++r2) {
            int row = blockIdx.x * 32 + rt * 16 + (l >> 4) * 4 + r2;
            if (row >= nRows) continue;
            float v = av[r2];
            if (col < 48) {
                if (col < L) X2[(size_t)row * L + col] = v + b2[col];
            } else {
                int q = max(-127, min(127, __float2int_rn(v * YSCALE)));
                Y2[(size_t)row * 64 + (col - 48)] = (signed char)q;
            }
        }
    }
}

// --- Layer 2 aggregation: out[r] = X2[batch[r]] + (1/32)*sum_j Y2[neigh[batch[r]][j]] ---
__global__ __launch_bounds__(256) void agg2_kernel(
    const float* __restrict__ X2,           // [N][L]
    const unsigned char* __restrict__ Y2,   // [N][64] int8
    const int* __restrict__ neigh,
    const int* __restrict__ batch,
    float* __restrict__ out,                // [B][L]
    int nRows, int L)
{
    const int tid = threadIdx.x, w = tid >> 6, l = tid & 63;
    const int jg = l >> 3;      // neighbor subgroup 0..7
    const int c = l & 7;        // 8B chunk of 64B row

    const int r0 = blockIdx.x * 16 + w * 4;
    int s[4];
    const int* nb[4];
#pragma unroll
    for (int rr = 0; rr < 4; ++rr) {
        int rc = min(r0 + rr, nRows - 1);
        s[rr] = batch[rc];
        nb[rr] = neigh + (size_t)s[rr] * DEG;
    }
    const char* yb = (const char*)Y2;
    const size_t co = (size_t)(8 * c);
#define YLD(j) (*(const uint2*)(yb + (size_t)(j) * 64 + co))
    uint2 v0[4], v1[4], v2[4], v3[4];
#pragma unroll
    for (int rr = 0; rr < 4; ++rr) {
        v0[rr] = YLD(nb[rr][jg]);
        v1[rr] = YLD(nb[rr][8 + jg]);
        v2[rr] = YLD(nb[rr][16 + jg]);
        v3[rr] = YLD(nb[rr][24 + jg]);
    }
#undef YLD

#pragma unroll
    for (int rr = 0; rr < 4; ++rr) {
        int iacc[8];
#pragma unroll
        for (int k = 0; k < 8; ++k) iacc[k] = 0;
#pragma unroll
        for (int q = 0; q < 4; ++q) {
            uint2 v = (q == 0) ? v0[rr] : (q == 1) ? v1[rr] : (q == 2) ? v2[rr] : v3[rr];
            unsigned x = v.x, y = v.y;
            iacc[0] += sxt8(x);       iacc[1] += sxt8(x >> 8);
            iacc[2] += sxt8(x >> 16); iacc[3] += sxt8(x >> 24);
            iacc[4] += sxt8(y);       iacc[5] += sxt8(y >> 8);
            iacc[6] += sxt8(y >> 16); iacc[7] += sxt8(y >> 24);
        }
#pragma unroll
        for (int k = 0; k < 8; ++k) {
            iacc[k] += __shfl_xor(iacc[k], 8);
            iacc[k] += __shfl_xor(iacc[k], 16);
            iacc[k] += __shfl_xor(iacc[k], 32);
        }
        int r = r0 + rr;
        if (jg == 0 && 8 * c < L && r < nRows) {
#pragma unroll
            for (int hv = 0; hv < 2; ++hv) {
                int colb = 8 * c + 4 * hv;
                if (colb < L) {
                    float4 xv = *(const float4*)(X2 + (size_t)s[rr] * L + colb);
                    float4 o;
                    o.x = xv.x + (float)iacc[4 * hv + 0] * YDEC;
                    o.y = xv.y + (float)iacc[4 * hv + 1] * YDEC;
                    o.z = xv.z + (float)iacc[4 * hv + 2] * YDEC;
                    o.w = xv.w + (float)iacc[4 * hv + 3] * YDEC;
                    *(float4*)(out + (size_t)r * L + colb) = o;
                }
            }
        }
    }
}

extern "C" void kernel_launch(void* const* d_in, const int* in_sizes, int n_in,
                              void* d_out, int out_size, void* d_ws, size_t ws_size,
                              hipStream_t stream) {
    const float* feats = (const float*)d_in[0];
    const int*   neigh = (const int*)d_in[1];
    const int*   batch = (const int*)d_in[2];
    const float* W1    = (const float*)d_in[3];
    const float* b1    = (const float*)d_in[4];
    const float* W2    = (const float*)d_in[5];
    const float* b2    = (const float*)d_in[6];

    const int N = in_sizes[0] / NFEAT;   // 50000
    const int B = in_sizes[2];           // 50000
    const int L = in_sizes[6];           // 40

    char* ws = (char*)d_ws;
    size_t off = 0;
    unsigned short* featsb = (unsigned short*)(ws + off); off += (size_t)N * NFEAT * 2;
    float*          X2     = (float*)(ws + off);          off += (size_t)N * L * 4;
    signed char*    Y2     = (signed char*)(ws + off);    off += (size_t)N * 64;
    unsigned char*  feats8 = (unsigned char*)(ws + off);  off += (size_t)N * NFEAT;
    unsigned short* W1p    = (unsigned short*)(ws + off); off += 8 * 8 * 64 * 8 * 2;
    unsigned short* W2p    = (unsigned short*)(ws + off); off += 7 * 4 * 64 * 8 * 2;

    int n4 = N * NFEAT / 4;
    int nPrepBlocks = (n4 + 255) / 256;
    int totalBlocks = nPrepBlocks + 128 + 56;
    prep_all_kernel<<<totalBlocks, 256, 0, stream>>>(
        feats, featsb, (unsigned*)feats8, W1, W1p, W2, W2p, n4, nPrepBlocks, L);

    layer1_fused_kernel<<<(N + 31) / 32, 512, 0, stream>>>(
        featsb, feats8, neigh, W1p, b1, W2p, b2, X2, Y2, N, L);

    agg2_kernel<<<(B + 15) / 16, 256, 0, stream>>>(
        X2, (const unsigned char*)Y2, neigh, batch, (float*)d_out, B, L);
}

// Round 13
// 143.297 us; speedup vs baseline: 1.1229x; 1.1229x over previous
//
#include <hip/hip_runtime.h>
#include <hip/hip_bf16.h>

typedef __attribute__((ext_vector_type(8))) short short8;
typedef __attribute__((ext_vector_type(4))) float f32x4;
typedef __attribute__((ext_vector_type(2))) short s16x2;

#define NFEAT 128
#define DEG 32
#define FSCALE 24.0f            // feats int8 scale
#define FDEC (1.0f / (24.0f * 32.0f))
#define YSCALE 64.0f            // Y2 int8 scale
#define YDEC (1.0f / (64.0f * 32.0f))

static __device__ __forceinline__ unsigned short f2bf(float f) {
    unsigned u = __float_as_uint(f);
    u += 0x7fffu + ((u >> 16) & 1u);   // round-to-nearest-even
    return (unsigned short)(u >> 16);
}
static __device__ __forceinline__ int sxt8(unsigned x) {
    return (int)(signed char)(x & 0xffu);
}
static __device__ __forceinline__ s16x2 shfl_pk(s16x2 v, int m) {
    int x = __builtin_bit_cast(int, v);
    x = __shfl_xor(x, m);
    return __builtin_bit_cast(s16x2, x);
}

// --- combined prep: feats cvt (bf16+int8) | pack W1 | pack W2 ---
__global__ void prep_all_kernel(const float* __restrict__ feats,
                                unsigned short* __restrict__ featsb,
                                unsigned* __restrict__ feats8,
                                const float* __restrict__ W1,
                                unsigned short* __restrict__ W1p,
                                const float* __restrict__ W2,
                                unsigned short* __restrict__ W2p,
                                int n4, int nPrepBlocks, int L) {
    int b = blockIdx.x;
    if (b < nPrepBlocks) {
        int i = b * 256 + threadIdx.x;
        if (i < n4) {
            float4 f = ((const float4*)feats)[i];
            ushort4 ob;
            ob.x = f2bf(f.x); ob.y = f2bf(f.y); ob.z = f2bf(f.z); ob.w = f2bf(f.w);
            ((ushort4*)featsb)[i] = ob;
            int a0 = max(-127, min(127, __float2int_rn(f.x * FSCALE)));
            int a1 = max(-127, min(127, __float2int_rn(f.y * FSCALE)));
            int a2 = max(-127, min(127, __float2int_rn(f.z * FSCALE)));
            int a3 = max(-127, min(127, __float2int_rn(f.w * FSCALE)));
            feats8[i] = (unsigned)(a0 & 0xff) | ((unsigned)(a1 & 0xff) << 8) |
                        ((unsigned)(a2 & 0xff) << 16) | ((unsigned)(a3 & 0xff) << 24);
        }
    } else if (b < nPrepBlocks + 128) {
        int t = (b - nPrepBlocks) * 256 + threadIdx.x;   // < 32768
        int j    = t & 7;
        int lane = (t >> 3) & 63;
        int ks   = (t >> 9) & 7;
        int nt   = t >> 12;
        int k    = ks * 32 + (lane >> 4) * 8 + j;
        int col  = nt * 16 + (lane & 15);
        W1p[t] = f2bf(W1[k * 128 + col]);
    } else {
        int t = (b - nPrepBlocks - 128) * 256 + threadIdx.x;
        if (t < 7 * 4 * 64 * 8) {
            int j    = t & 7;
            int lane = (t >> 3) & 63;
            int ks   = (t >> 9) & 3;
            int nt   = t >> 11;
            int k    = ks * 32 + (lane >> 4) * 8 + j;
            int p    = nt * 16 + (lane & 15);
            float v = 0.f;
            if (p < 48) { if (p < L) v = W2[k * L + p]; }
            else        { int cc = p - 48; if (cc < L) v = W2[(128 + k) * L + cc]; }
            W2p[t] = f2bf(v);
        }
    }
}

// --- fused layer1+gemm2: 512 thr / 8 waves / 32 rows per block ---
// __launch_bounds__(512,4): VGPR budget 128 — R11's (512,8) capped VGPR at 32
// and spilled the gather window to scratch (WRITE_SIZE 11->55MB). 2-3 resident
// blocks/CU (16-24 waves) is enough; spills are not acceptable.
__global__ __launch_bounds__(512, 4) void layer1_fused_kernel(
    const unsigned short* __restrict__ tableb,  // featsb [N][128] bf16
    const unsigned char* __restrict__ table8,   // feats8 [N][128] int8
    const int* __restrict__ neigh,              // [N][32]
    const unsigned short* __restrict__ W1p,
    const float* __restrict__ b1,
    const unsigned short* __restrict__ W2p,
    const float* __restrict__ b2,
    float* __restrict__ X2,                     // [N][L]
    signed char* __restrict__ Y2,               // [N][64]
    int nRows, int L)
{
    __shared__ unsigned int z1[32 * 128];     // 16 KB: 32 rows x 512B, XOR-swizzled
    __shared__ unsigned int h1s[32 * 68];     // 8.5 KB: 32 rows x 272B (bank-skewed)
    const int tid = threadIdx.x;
    const int w = tid >> 6;       // wave 0..7
    const int l = tid & 63;
    const int jg = l >> 3;        // neighbor subgroup 0..7 (owns 4 neighbors)
    const int c = l & 7;          // 16B chunk of the 128B int8 row

    // ---- self rows (bf16): 512 threads x 1 uint4 covers 32 rows ----
    int srow = tid >> 4, sch = tid & 15;
    int sr = min(blockIdx.x * 32 + srow, nRows - 1);
    uint4 selfv = ((const uint4*)(tableb + (size_t)sr * NFEAT))[sch];

    // ---- neighbor indices for the wave's 4 rows ----
    const int r0 = blockIdx.x * 32 + w * 4;
    const int* nbp0 = neigh + (size_t)min(r0 + 0, nRows - 1) * DEG;
    const int* nbp1 = neigh + (size_t)min(r0 + 1, nRows - 1) * DEG;
    const int* nbp2 = neigh + (size_t)min(r0 + 2, nRows - 1) * DEG;
    const int* nbp3 = neigh + (size_t)min(r0 + 3, nRows - 1) * DEG;
    int i00 = nbp0[jg], i01 = nbp0[8 + jg], i02 = nbp0[16 + jg], i03 = nbp0[24 + jg];
    int i10 = nbp1[jg], i11 = nbp1[8 + jg], i12 = nbp1[16 + jg], i13 = nbp1[24 + jg];
    int i20 = nbp2[jg], i21 = nbp2[8 + jg], i22 = nbp2[16 + jg], i23 = nbp2[24 + jg];
    int i30 = nbp3[jg], i31 = nbp3[8 + jg], i32 = nbp3[16 + jg], i33 = nbp3[24 + jg];

    const char* tb8 = (const char*)table8;
    const size_t co = (size_t)(16 * c);
#define GLD16(j) (*(const uint4*)(tb8 + (size_t)(j) * 128 + co))
#define GATH4(A, a, b_, c_, d_) \
    uint4 A##0 = GLD16(a), A##1 = GLD16(b_), A##2 = GLD16(c_), A##3 = GLD16(d_);

    GATH4(vA, i00, i01, i02, i03)
    GATH4(vB, i10, i11, i12, i13)

    // self-row LDS write (waits only on selfv)
    *(uint4*)((char*)z1 + srow * 512 + ((16 * sch) ^ ((srow & 7) << 4))) = selfv;

    GATH4(vC, i20, i21, i22, i23)

    // packed-i16 consume: e[d]={f+0,f+2}, o[d]={f+1,f+3} per dword d
#define UNPK_PK(vd, d)                                                        \
    {                                                                         \
        unsigned _v = (vd);                                                   \
        e[d] += (__builtin_bit_cast(s16x2, (unsigned)(_v << 8)) >> 8);        \
        o[d] += (__builtin_bit_cast(s16x2, _v) >> 8);                         \
    }
#define CONSUME_PK(A, rowi)                                                          \
    {                                                                                \
        uint4 q0 = A##0, q1 = A##1, q2 = A##2, q3 = A##3;                            \
        s16x2 e[4] = {(s16x2)0, (s16x2)0, (s16x2)0, (s16x2)0};                       \
        s16x2 o[4] = {(s16x2)0, (s16x2)0, (s16x2)0, (s16x2)0};                       \
        UNPK_PK(q0.x, 0) UNPK_PK(q0.y, 1) UNPK_PK(q0.z, 2) UNPK_PK(q0.w, 3)          \
        UNPK_PK(q1.x, 0) UNPK_PK(q1.y, 1) UNPK_PK(q1.z, 2) UNPK_PK(q1.w, 3)          \
        UNPK_PK(q2.x, 0) UNPK_PK(q2.y, 1) UNPK_PK(q2.z, 2) UNPK_PK(q2.w, 3)          \
        UNPK_PK(q3.x, 0) UNPK_PK(q3.y, 1) UNPK_PK(q3.z, 2) UNPK_PK(q3.w, 3)          \
        _Pragma("unroll") for (int d = 0; d < 4; ++d) {                              \
            e[d] += shfl_pk(e[d], 8);  o[d] += shfl_pk(o[d], 8);                     \
            e[d] += shfl_pk(e[d], 16); o[d] += shfl_pk(o[d], 16);                    \
            e[d] += shfl_pk(e[d], 32); o[d] += shfl_pk(o[d], 32);                    \
        }                                                                            \
        if (jg == 0) {                                                               \
            int row = w * 4 + rowi;                                                  \
            int swz = (row & 7) << 4;                                                \
            uint4 m0, m1;                                                            \
            unsigned* mw0 = (unsigned*)&m0;                                          \
            unsigned* mw1 = (unsigned*)&m1;                                          \
            _Pragma("unroll") for (int d = 0; d < 2; ++d) {                          \
                mw0[2*d]   = ((unsigned)f2bf((float)o[d].x * FDEC) << 16) |          \
                             (unsigned)f2bf((float)e[d].x * FDEC);                   \
                mw0[2*d+1] = ((unsigned)f2bf((float)o[d].y * FDEC) << 16) |          \
                             (unsigned)f2bf((float)e[d].y * FDEC);                   \
                mw1[2*d]   = ((unsigned)f2bf((float)o[d+2].x * FDEC) << 16) |        \
                             (unsigned)f2bf((float)e[d+2].x * FDEC);                 \
                mw1[2*d+1] = ((unsigned)f2bf((float)o[d+2].y * FDEC) << 16) |        \
                             (unsigned)f2bf((float)e[d+2].y * FDEC);                 \
            }                                                                        \
            *(uint4*)((char*)z1 + row * 512 + ((256 + 32 * c) ^ swz)) = m0;          \
            *(uint4*)((char*)z1 + row * 512 + ((256 + 32 * c + 16) ^ swz)) = m1;     \
        }                                                                            \
    }

    CONSUME_PK(vA, 0)
    GATH4(vD, i30, i31, i32, i33)
    CONSUME_PK(vB, 1)
    CONSUME_PK(vC, 2)
    CONSUME_PK(vD, 3)
#undef GLD16
#undef GATH4
#undef UNPK_PK
#undef CONSUME_PK
    __syncthreads();

    // ---- Phase 2: [32 x 256] @ [256 x 128] -> h1 ----
    // wave w: row-tile rt = w>>2 (rows rt*16..+15), n-tiles nt0=(w&3)*2, nt0+1
    f32x4 macc0 = (f32x4){0.f,0.f,0.f,0.f}, macc1 = (f32x4){0.f,0.f,0.f,0.f};
    const int rt = w >> 2;
    const int nt0 = (w & 3) * 2;
    {
        const int arow = rt * 16 + (l & 15);
        const int aswz = (arow & 7) << 4;
        const char* zbase = (const char*)z1 + arow * 512;
#pragma unroll
        for (int ks = 0; ks < 8; ++ks) {
            int kb = (ks * 64 + ((l >> 4) * 16)) ^ aswz;
            short8 a = *(const short8*)(zbase + kb);
            short8 b0 = *(const short8*)(W1p + ((size_t)((nt0 + 0) * 8 + ks) * 64 + l) * 8);
            short8 b1f = *(const short8*)(W1p + ((size_t)((nt0 + 1) * 8 + ks) * 64 + l) * 8);
            macc0 = __builtin_amdgcn_mfma_f32_16x16x32_bf16(a, b0, macc0, 0, 0, 0);
            macc1 = __builtin_amdgcn_mfma_f32_16x16x32_bf16(a, b1f, macc1, 0, 0, 0);
        }
    }

    // ---- Phase 3a: bias+relu, h1 tile [32][128] bf16 -> h1s (272B row stride) ----
    // no barrier needed vs phase2: different LDS buffer, macc dependency orders us
#pragma unroll
    for (int tt = 0; tt < 2; ++tt) {
        int col = (nt0 + tt) * 16 + (l & 15);
        float bv = b1[col];
        f32x4 m = tt ? macc1 : macc0;
#pragma unroll
        for (int r2 = 0; r2 < 4; ++r2) {
            int row = rt * 16 + (l >> 4) * 4 + r2;
            float v = fmaxf(m[r2] + bv, 0.f);
            *(unsigned short*)((char*)h1s + row * 272 + col * 2) = f2bf(v);
        }
    }
    __syncthreads();

    // ---- Phase 3b: [32 x 128] @ [128 x 112p] -> X2/Y2 ----
    f32x4 acc2a = (f32x4){0.f,0.f,0.f,0.f}, acc2b = (f32x4){0.f,0.f,0.f,0.f};
    const int ntA = w & 3, ntB = 4 + (w & 3);
    {
        const int arow = rt * 16 + (l & 15);
        const char* hb = (const char*)h1s + arow * 272;
#pragma unroll
        for (int ks2 = 0; ks2 < 4; ++ks2) {
            short8 a = *(const short8*)(hb + ks2 * 64 + ((l >> 4) * 16));
            short8 bA = *(const short8*)(W2p + ((size_t)(ntA * 4 + ks2) * 64 + l) * 8);
            acc2a = __builtin_amdgcn_mfma_f32_16x16x32_bf16(a, bA, acc2a, 0, 0, 0);
            if (ntB < 7) {
                short8 bB = *(const short8*)(W2p + ((size_t)(ntB * 4 + ks2) * 64 + l) * 8);
                acc2b = __builtin_amdgcn_mfma_f32_16x16x32_bf16(a, bB, acc2b, 0, 0, 0);
            }
        }
    }

    // ---- epilogue: X2 f32 (+b2) cols<48, Y2 int8 cols 48..111 ----
#pragma unroll
    for (int part = 0; part < 2; ++part) {
        int nt = part ? ntB : ntA;
        if (nt >= 7) continue;
        f32x4 av = part ? acc2b : acc2a;
        int col = nt * 16 + (l & 15);
#pragma unroll
        for (int r2 = 0; r2 < 4; ++r2) {
            int row = blockIdx.x * 32 + rt * 16 + (l >> 4) * 4 + r2;
            if (row >= nRows) continue;
            float v = av[r2];
            if (col < 48) {
                if (col < L) X2[(size_t)row * L + col] = v + b2[col];
            } else {
                int q = max(-127, min(127, __float2int_rn(v * YSCALE)));
                Y2[(size_t)row * 64 + (col - 48)] = (signed char)q;
            }
        }
    }
}

// --- Layer 2 aggregation: out[r] = X2[batch[r]] + (1/32)*sum_j Y2[neigh[batch[r]][j]] ---
__global__ __launch_bounds__(256) void agg2_kernel(
    const float* __restrict__ X2,           // [N][L]
    const unsigned char* __restrict__ Y2,   // [N][64] int8
    const int* __restrict__ neigh,
    const int* __restrict__ batch,
    float* __restrict__ out,                // [B][L]
    int nRows, int L)
{
    const int tid = threadIdx.x, w = tid >> 6, l = tid & 63;
    const int jg = l >> 3;      // neighbor subgroup 0..7
    const int c = l & 7;        // 8B chunk of 64B row

    const int r0 = blockIdx.x * 16 + w * 4;
    int s[4];
    const int* nb[4];
#pragma unroll
    for (int rr = 0; rr < 4; ++rr) {
        int rc = min(r0 + rr, nRows - 1);
        s[rr] = batch[rc];
        nb[rr] = neigh + (size_t)s[rr] * DEG;
    }
    const char* yb = (const char*)Y2;
    const size_t co = (size_t)(8 * c);
#define YLD(j) (*(const uint2*)(yb + (size_t)(j) * 64 + co))
    uint2 v0[4], v1[4], v2[4], v3[4];
#pragma unroll
    for (int rr = 0; rr < 4; ++rr) {
        v0[rr] = YLD(nb[rr][jg]);
        v1[rr] = YLD(nb[rr][8 + jg]);
        v2[rr] = YLD(nb[rr][16 + jg]);
        v3[rr] = YLD(nb[rr][24 + jg]);
    }
#undef YLD

#pragma unroll
    for (int rr = 0; rr < 4; ++rr) {
        int iacc[8];
#pragma unroll
        for (int k = 0; k < 8; ++k) iacc[k] = 0;
#pragma unroll
        for (int q = 0; q < 4; ++q) {
            uint2 v = (q == 0) ? v0[rr] : (q == 1) ? v1[rr] : (q == 2) ? v2[rr] : v3[rr];
            unsigned x = v.x, y = v.y;
            iacc[0] += sxt8(x);       iacc[1] += sxt8(x >> 8);
            iacc[2] += sxt8(x >> 16); iacc[3] += sxt8(x >> 24);
            iacc[4] += sxt8(y);       iacc[5] += sxt8(y >> 8);
            iacc[6] += sxt8(y >> 16); iacc[7] += sxt8(y >> 24);
        }
#pragma unroll
        for (int k = 0; k < 8; ++k) {
            iacc[k] += __shfl_xor(iacc[k], 8);
            iacc[k] += __shfl_xor(iacc[k], 16);
            iacc[k] += __shfl_xor(iacc[k], 32);
        }
        int r = r0 + rr;
        if (jg == 0 && 8 * c < L && r < nRows) {
#pragma unroll
            for (int hv = 0; hv < 2; ++hv) {
                int colb = 8 * c + 4 * hv;
                if (colb < L) {
                    float4 xv = *(const float4*)(X2 + (size_t)s[rr] * L + colb);
                    float4 o;
                    o.x = xv.x + (float)iacc[4 * hv + 0] * YDEC;
                    o.y = xv.y + (float)iacc[4 * hv + 1] * YDEC;
                    o.z = xv.z + (float)iacc[4 * hv + 2] * YDEC;
                    o.w = xv.w + (float)iacc[4 * hv + 3] * YDEC;
                    *(float4*)(out + (size_t)r * L + colb) = o;
                }
            }
        }
    }
}

extern "C" void kernel_launch(void* const* d_in, const int* in_sizes, int n_in,
                              void* d_out, int out_size, void* d_ws, size_t ws_size,
                              hipStream_t stream) {
    const float* feats = (const float*)d_in[0];
    const int*   neigh = (const int*)d_in[1];
    const int*   batch = (const int*)d_in[2];
    const float* W1    = (const float*)d_in[3];
    const float* b1    = (const float*)d_in[4];
    const float* W2    = (const float*)d_in[5];
    const float* b2    = (const float*)d_in[6];

    const int N = in_sizes[0] / NFEAT;   // 50000
    const int B = in_sizes[2];           // 50000
    const int L = in_sizes[6];           // 40

    char* ws = (char*)d_ws;
    size_t off = 0;
    unsigned short* featsb = (unsigned short*)(ws + off); off += (size_t)N * NFEAT * 2;
    float*          X2     = (float*)(ws + off);          off += (size_t)N * L * 4;
    signed char*    Y2     = (signed char*)(ws + off);    off += (size_t)N * 64;
    unsigned char*  feats8 = (unsigned char*)(ws + off);  off += (size_t)N * NFEAT;
    unsigned short* W1p    = (unsigned short*)(ws + off); off += 8 * 8 * 64 * 8 * 2;
    unsigned short* W2p    = (unsigned short*)(ws + off); off += 7 * 4 * 64 * 8 * 2;

    int n4 = N * NFEAT / 4;
    int nPrepBlocks = (n4 + 255) / 256;
    int totalBlocks = nPrepBlocks + 128 + 56;
    prep_all_kernel<<<totalBlocks, 256, 0, stream>>>(
        feats, featsb, (unsigned*)feats8, W1, W1p, W2, W2p, n4, nPrepBlocks, L);

    layer1_fused_kernel<<<(N + 31) / 32, 512, 0, stream>>>(
        featsb, feats8, neigh, W1p, b1, W2p, b2, X2, Y2, N, L);

    agg2_kernel<<<(B + 15) / 16, 256, 0, stream>>>(
        X2, (const unsigned char*)Y2, neigh, batch, (float*)d_out, B, L);
}